// Round 2
// baseline (33.798 us; speedup 1.0000x reference)
//
#include <hip/hip_runtime.h>

// CyclicShiftConv collapse (proven R1, absmax 0.0):
//   softmax over R=4 identical logits == 0.25 exactly =>
//   out[b,c,l] = 0.25 * sum_r x[b,c, rot_idx[r,l]].
//
// Further structure exploited here:
//   * rot_idx[0] is the identity permutation (angle 0), and each thread's
//     staged quad == its output quad => r=0 contribution stays in registers.
//   * Hilbert quads: d in [4k,4k+4) is an aligned 2x2 cell block; grid
//     rotations map aligned 2x2 blocks to aligned 2x2 blocks, so
//     rot_idx[r, 4k..4k+3] is a permutation of [4k',4k'+4). Each rotation
//     needs only a 10-bit base-quad + 8-bit intra-quad perm. All three
//     rotations pack into one uint2 per quad (8 B vs the 64 B of raw int4
//     index loads in R1 -> 256 MiB of L2 index traffic becomes 32 MiB).

constexpr int Lq  = 4096;        // N*N
constexpr int NQ  = Lq / 4;      // 1024 quads per row
constexpr int BC  = 16 * 256;    // B*C rows

__global__ __launch_bounds__(256) void prep_kernel(
    const int* __restrict__ rot, uint2* __restrict__ meta) {
  const int q = blockIdx.x * 256 + threadIdx.x;   // quad id, [0, NQ)
  const int4* r90  = reinterpret_cast<const int4*>(rot + Lq);
  const int4* r180 = reinterpret_cast<const int4*>(rot + 2 * Lq);
  const int4* r270 = reinterpret_cast<const int4*>(rot + 3 * Lq);
  const int4 a = r90[q], b = r180[q], c = r270[q];
  const uint b90  = (uint)a.x >> 2;   // base quad index (all 4 share it)
  const uint b180 = (uint)b.x >> 2;
  const uint b270 = (uint)c.x >> 2;
  const uint p90  = (uint)(a.x & 3) | ((uint)(a.y & 3) << 2) |
                    ((uint)(a.z & 3) << 4) | ((uint)(a.w & 3) << 6);
  const uint p180 = (uint)(b.x & 3) | ((uint)(b.y & 3) << 2) |
                    ((uint)(b.z & 3) << 4) | ((uint)(b.w & 3) << 6);
  const uint p270 = (uint)(c.x & 3) | ((uint)(c.y & 3) << 2) |
                    ((uint)(c.z & 3) << 4) | ((uint)(c.w & 3) << 6);
  meta[q] = make_uint2(b90 | (b180 << 10) | (b270 << 20),
                       p90 | (p180 << 8) | (p270 << 16));
}

__device__ __forceinline__ float sel(const float4 q, const uint c) {
  // 2-bit runtime select; compiles to a cndmask chain (no scratch).
  return c == 0u ? q.x : (c == 1u ? q.y : (c == 2u ? q.z : q.w));
}

__global__ __launch_bounds__(256) void rotavg_kernel(
    const float* __restrict__ x,
    const uint2* __restrict__ meta,
    float*       __restrict__ out) {
  __shared__ float4 row4[NQ];

  const int bc = blockIdx.x;
  const float4* xr4 = reinterpret_cast<const float4*>(x + (size_t)bc * Lq);
  float4*       o4  = reinterpret_cast<float4*>(out + (size_t)bc * Lq);
  const int t = threadIdx.x;

  float4 xq[4];     // own quads == r=0 contribution, kept in registers
  uint2  mm[4];     // meta prefetched during staging (overlaps barrier)
#pragma unroll
  for (int i = 0; i < 4; ++i) {
    const int e = t + i * 256;
    xq[i] = xr4[e];
    row4[e] = xq[i];
    mm[i] = meta[e];
  }
  __syncthreads();

#pragma unroll
  for (int i = 0; i < 4; ++i) {
    const int e = t + i * 256;
    const uint2 m = mm[i];
    const float4 q90  = row4[m.x & 1023u];
    const float4 q180 = row4[(m.x >> 10) & 1023u];
    const float4 q270 = row4[(m.x >> 20) & 1023u];
    const uint p = m.y;
    float4 v;
    v.x = 0.25f * (xq[i].x + sel(q90, p & 3u)         + sel(q180, (p >> 8) & 3u)  + sel(q270, (p >> 16) & 3u));
    v.y = 0.25f * (xq[i].y + sel(q90, (p >> 2) & 3u)  + sel(q180, (p >> 10) & 3u) + sel(q270, (p >> 18) & 3u));
    v.z = 0.25f * (xq[i].z + sel(q90, (p >> 4) & 3u)  + sel(q180, (p >> 12) & 3u) + sel(q270, (p >> 20) & 3u));
    v.w = 0.25f * (xq[i].w + sel(q90, (p >> 6) & 3u)  + sel(q180, (p >> 14) & 3u) + sel(q270, (p >> 22) & 3u));
    o4[e] = v;
  }
}

extern "C" void kernel_launch(void* const* d_in, const int* in_sizes, int n_in,
                              void* d_out, int out_size, void* d_ws, size_t ws_size,
                              hipStream_t stream) {
  const float* x       = (const float*)d_in[0];
  const int*   rot_idx = (const int*)d_in[1];
  // d_in[2..5] = w1, b1, w2, b2 — mathematically dead (softmax of equal logits).
  float* out = (float*)d_out;
  uint2* meta = (uint2*)d_ws;   // 1024 * 8 B = 8 KiB scratch

  prep_kernel<<<NQ / 256, 256, 0, stream>>>(rot_idx, meta);
  rotavg_kernel<<<BC, 256, 0, stream>>>(x, meta, out);
}

// Round 3
// 26.520 us; speedup vs baseline: 1.2744x; 1.2744x over previous
//
#include <hip/hip_runtime.h>

// CyclicShiftConv collapse (proven R1/R2, absmax 0.0):
//   Every rot_idx row is a permutation of [0,L) => s[b,c,r] is r-independent
//   => softmax over R=4 equal logits == exactly 0.25 =>
//   out[b,c,l] = 0.25 * (x[b,c,l] + sum_{r=1..3} x[b,c, rot_idx[r,l]]).
//   (rot_idx[0] is the identity; w1/b1/w2/b2 are mathematically dead.)
//
// R3 structure: amortize the index loads. Each block processes ROWS=4 (b,c)
// rows; the per-thread index set is identical across rows, so it is loaded
// ONCE (12 int4/thread) and kept packed in 24 VGPRs (2 x 12-bit per uint).
// Index L2 traffic: 256 MiB (R1) -> 48 MiB. Row data is double-buffered in
// LDS (2 x 16 KiB) with one barrier per row; the r=0 term comes straight
// from the staging registers.

constexpr int L    = 4096;           // N*N
constexpr int ROWS = 4;              // rows per block
constexpr int NB   = (16 * 256) / ROWS;  // 1024 blocks

__global__ __launch_bounds__(256) void rotavg_kernel(
    const float* __restrict__ x,
    const int*   __restrict__ rot,
    float*       __restrict__ out) {
  __shared__ float row[2][L];        // 32 KiB -> 4 blocks/CU (grid = 4/CU)

  const int t = threadIdx.x;
  const size_t row0 = (size_t)blockIdx.x * ROWS;

  // ---- load + pack this thread's indices once (rotations 1..3 only) ----
  unsigned pk[24];                   // [i*6 + r*2 + k], all compile-time after unroll
#pragma unroll
  for (int i = 0; i < 4; ++i) {
    const int e = t + i * 256;
#pragma unroll
    for (int r = 0; r < 3; ++r) {
      const int4 v = reinterpret_cast<const int4*>(rot + (r + 1) * L)[e];
      pk[i * 6 + r * 2 + 0] = (unsigned)v.x | ((unsigned)v.y << 16);
      pk[i * 6 + r * 2 + 1] = (unsigned)v.z | ((unsigned)v.w << 16);
    }
  }

  // ---- prologue: first row into registers ----
  float4 cur[4], nxt[4];
  {
    const float4* xr4 = reinterpret_cast<const float4*>(x + row0 * L);
#pragma unroll
    for (int i = 0; i < 4; ++i) cur[i] = xr4[t + i * 256];
  }

#pragma unroll
  for (int j = 0; j < ROWS; ++j) {
    const int buf = j & 1;
    float4* r4 = reinterpret_cast<float4*>(&row[buf][0]);
#pragma unroll
    for (int i = 0; i < 4; ++i) r4[t + i * 256] = cur[i];
    __syncthreads();   // row[buf] visible; double-buffer needs only this one

    // issue next row's loads (overlap with gather below)
    if (j + 1 < ROWS) {
      const float4* xn4 = reinterpret_cast<const float4*>(x + (row0 + j + 1) * L);
#pragma unroll
      for (int i = 0; i < 4; ++i) nxt[i] = xn4[t + i * 256];
    }

    const float* rb = &row[buf][0];
    float4* o4 = reinterpret_cast<float4*>(out + (row0 + j) * L);
#pragma unroll
    for (int i = 0; i < 4; ++i) {
      const unsigned a0 = pk[i * 6 + 0], a1 = pk[i * 6 + 1];
      const unsigned b0 = pk[i * 6 + 2], b1 = pk[i * 6 + 3];
      const unsigned c0 = pk[i * 6 + 4], c1 = pk[i * 6 + 5];
      float4 v;
      v.x = 0.25f * (cur[i].x + rb[a0 & 0xFFFu] + rb[b0 & 0xFFFu] + rb[c0 & 0xFFFu]);
      v.y = 0.25f * (cur[i].y + rb[a0 >> 16]    + rb[b0 >> 16]    + rb[c0 >> 16]);
      v.z = 0.25f * (cur[i].z + rb[a1 & 0xFFFu] + rb[b1 & 0xFFFu] + rb[c1 & 0xFFFu]);
      v.w = 0.25f * (cur[i].w + rb[a1 >> 16]    + rb[b1 >> 16]    + rb[c1 >> 16]);
      o4[t + i * 256] = v;
    }

    if (j + 1 < ROWS) {
#pragma unroll
      for (int i = 0; i < 4; ++i) cur[i] = nxt[i];
    }
  }
}

extern "C" void kernel_launch(void* const* d_in, const int* in_sizes, int n_in,
                              void* d_out, int out_size, void* d_ws, size_t ws_size,
                              hipStream_t stream) {
  const float* x       = (const float*)d_in[0];
  const int*   rot_idx = (const int*)d_in[1];
  // d_in[2..5] = w1, b1, w2, b2 — mathematically dead (softmax of equal logits).
  float* out = (float*)d_out;

  rotavg_kernel<<<NB, 256, 0, stream>>>(x, rot_idx, out);
}